// Round 4
// baseline (943.214 us; speedup 1.0000x reference)
//
#include <hip/hip_runtime.h>

#define N_GRAPHS    8
#define EDGES_PER_G 2048
#define NN          8192
#define EE          16384
#define IN_DIM      10
#define EDGE_DIM    9
#define HID         64
#define OUT_DIM     3
#define TT          5
#define EPSN        1e-6f

typedef float f32x4 __attribute__((ext_vector_type(4)));
typedef short bf16x8s __attribute__((ext_vector_type(8)));

union BF8 { __bf16 h[8]; bf16x8s v; };

// ---------------- edge MLP, one edge per LANE, transposed output h2T[c][e] -------
// h2T[c*EE+e] = relu(relu(norm(ear[e]) @ w1 + b1) @ w2 + b2)[c]
__device__ inline void edgemlp_lane(int e,
    const float* __restrict__ ear, const float* __restrict__ meanb,
    const float* __restrict__ invstd,
    const float* __restrict__ w1, const float* __restrict__ b1,
    const float* __restrict__ w2, const float* __restrict__ b2,
    float* __restrict__ h2T) {
  int gg = e >> 11;                        // 2048 edges per graph
  const float* er = ear + (size_t)e * EDGE_DIM;
  const float* mb = meanb + gg * EDGE_DIM;
  const float* is = invstd + gg * EDGE_DIM;
  float xn[EDGE_DIM];
#pragma unroll
  for (int d = 0; d < EDGE_DIM; ++d) xn[d] = (er[d] - mb[d]) * is[d];
  float h1[HID];
#pragma unroll 8
  for (int ch = 0; ch < HID; ++ch) {
    float a = b1[ch];
#pragma unroll
    for (int d = 0; d < EDGE_DIM; ++d) a += xn[d] * w1[d * HID + ch];
    h1[ch] = fmaxf(a, 0.f);
  }
#pragma unroll 4
  for (int c2 = 0; c2 < HID; ++c2) {
    float o = b2[c2];
#pragma unroll 8
    for (int h = 0; h < HID; ++h) o += h1[h] * w2[h * HID + c2];
    h2T[(size_t)c2 * EE + e] = fmaxf(o, 0.f);
  }
}

// ---------------- preamble: lift | bprep(permuted) | deg | stats | zero-aggr ------
__global__ __launch_bounds__(256) void k_pre(
    const float* __restrict__ x,
    const float* __restrict__ lw1, const float* __restrict__ lb1,
    const float* __restrict__ lw2, const float* __restrict__ lb2,
    float* __restrict__ v,
    const float* __restrict__ kw3, const float* __restrict__ kb3,
    unsigned short* __restrict__ Bbf,
    const int* __restrict__ dst, float* __restrict__ degf,
    const float* __restrict__ ear, float* __restrict__ meanb,
    float* __restrict__ invstd, float* __restrict__ aggr) {
  __shared__ float sh[4][HID];
  int b = blockIdx.x;
  int g = threadIdx.x >> 6, lane = threadIdx.x & 63;
  if (b < NN / 4) {
    // ---- lift MLP ----
    int n = b * 4 + g;
    const float* xr = x + n * IN_DIM;
    float a = lb1[lane];
#pragma unroll
    for (int d = 0; d < IN_DIM; ++d) a += xr[d] * lw1[d * HID + lane];
    sh[g][lane] = fmaxf(a, 0.f);
    __syncthreads();
    float o = lb2[lane];
#pragma unroll
    for (int h = 0; h < HID; ++h) o += sh[g][h] * lw2[h * HID + lane];
    v[n * HID + lane] = o;
  } else if (b < NN / 4 + 1024) {
    // ---- bprep: kw3 (+kb3 as row 64) -> bf16, FRAGMENT-MAJOR layout:
    //      Bbf[t][c][(s*4+nt)*512 + lane*8 + jj], element = W3[c][nt*16+n15][s*32+q*8+jj]
    const int total = TT * 65 * 4096;
    for (int i = (b - NN / 4) * 256 + (int)threadIdx.x; i < total; i += 1024 * 256) {
      int xx   = i & 4095;
      int call = i >> 12;
      int t = call / 65;
      int c = call - t * 65;
      int sn = xx >> 9;              // s*4+nt
      int s  = sn >> 2, nt = sn & 3;
      int l9 = xx & 511;
      int ln = l9 >> 3, jj = l9 & 7;
      int nn15 = ln & 15, qq = ln >> 4;
      int x_in = (nt * 16 + nn15) * 64 + s * 32 + qq * 8 + jj;
      float val = (c < 64) ? kw3[(size_t)(t * 64 + c) * 4096 + x_in]
                           : kb3[(size_t)t * 4096 + x_in];
      union { __bf16 h; unsigned short s16; } u;
      u.h = (__bf16)val;
      Bbf[i] = u.s16;
    }
  } else if (b < NN / 4 + 1024 + EE / 256) {
    // ---- deg histogram ----
    int e = (b - (NN / 4 + 1024)) * 256 + threadIdx.x;
    atomicAdd(&degf[dst[e]], 1.f);
  } else if (b < NN / 4 + 1024 + EE / 256 + N_GRAPHS) {
    // ---- per-graph edge_attr stats ----
    int gg = b - (NN / 4 + 1024 + EE / 256);
    float* ssum = &sh[0][0];
    float* ssq  = &sh[1][0];
    if (threadIdx.x < EDGE_DIM) { ssum[threadIdx.x] = 0.f; ssq[threadIdx.x] = 0.f; }
    __syncthreads();
    float ls[EDGE_DIM], lq[EDGE_DIM];
#pragma unroll
    for (int d = 0; d < EDGE_DIM; ++d) { ls[d] = 0.f; lq[d] = 0.f; }
    for (int e = threadIdx.x; e < EDGES_PER_G; e += blockDim.x) {
      const float* row = ear + (size_t)(gg * EDGES_PER_G + e) * EDGE_DIM;
#pragma unroll
      for (int d = 0; d < EDGE_DIM; ++d) { float xv = row[d]; ls[d] += xv; lq[d] += xv * xv; }
    }
#pragma unroll
    for (int d = 0; d < EDGE_DIM; ++d) { atomicAdd(&ssum[d], ls[d]); atomicAdd(&ssq[d], lq[d]); }
    __syncthreads();
    if (threadIdx.x < EDGE_DIM) {
      float m  = ssum[threadIdx.x] * (1.0f / EDGES_PER_G);
      float mq = ssq[threadIdx.x] * (1.0f / EDGES_PER_G);
      float var = fmaxf(mq - m * m, 0.f);
      meanb[gg * EDGE_DIM + threadIdx.x]  = m;
      invstd[gg * EDGE_DIM + threadIdx.x] = 1.f / (sqrtf(var) + EPSN);
    }
  } else {
    // ---- zero aggr (float4, 512 blocks) ----
    int idx = (b - (NN / 4 + 1024 + EE / 256 + N_GRAPHS)) * 256 + threadIdx.x;
    ((float4*)aggr)[idx] = make_float4(0.f, 0.f, 0.f, 0.f);
  }
}

// ---------------- standalone edge MLP (layer 0), 64 blocks ----------------
__global__ __launch_bounds__(256) void k_em(const float* __restrict__ ear,
    const float* __restrict__ meanb, const float* __restrict__ invstd,
    const float* __restrict__ w1, const float* __restrict__ b1,
    const float* __restrict__ w2, const float* __restrict__ b2,
    float* __restrict__ h2T) {
  int e = blockIdx.x * 256 + threadIdx.x;
  edgemlp_lane(e, ear, meanb, invstd, w1, b1, w2, b2, h2T);
}

// ---------------- msg GEMM: Msg[E,64] = A[E,4160] @ B[4160,64], scatter by dst ----
// A[e, c*64+j] = h2[e,c] * v[src[e], j]  (row c==64: h2==1 -> bias b3)
// B in fragment-major layout: every fragment load is base + lane*16 (coalesced).
// h2 in transposed layout h2T[c][e]: per-iter load = 16 consecutive floats.
__global__ __launch_bounds__(256) void k_msg(const float* __restrict__ v,
    const float* __restrict__ h2T, const unsigned short* __restrict__ Bt,
    const int* __restrict__ src, const int* __restrict__ dst,
    float* __restrict__ aggr) {
  int kchunk = blockIdx.x & 3;
  int ebb    = (blockIdx.x >> 2) * 128;
  int w    = threadIdx.x >> 6;
  int lane = threadIdx.x & 63;
  int n15  = lane & 15;
  int q    = lane >> 4;
  int ebase = ebb + w * 32;

  float4 vs[2][2][2];   // [m-tile][k-step s][half]: v[src[e]][s*32 + q*8 .. +8]
#pragma unroll
  for (int mt = 0; mt < 2; ++mt) {
    int e = ebase + mt * 16 + n15;
    const float4* vr = (const float4*)(v + (size_t)src[e] * HID);
    int f0 = q * 2;
    vs[mt][0][0] = vr[f0];     vs[mt][0][1] = vr[f0 + 1];
    vs[mt][1][0] = vr[8 + f0]; vs[mt][1][1] = vr[8 + f0 + 1];
  }

  f32x4 acc[2][4];
#pragma unroll
  for (int mt = 0; mt < 2; ++mt)
#pragma unroll
    for (int nt = 0; nt < 4; ++nt) acc[mt][nt] = (f32x4)0.0f;

  int c0 = kchunk * 16;
  const unsigned short* Bp = Bt + (size_t)c0 * 4096 + lane * 8;
  const float* hp = h2T + (size_t)c0 * EE + ebase + n15;

#pragma unroll 4
  for (int cc = 0; cc < 16; ++cc) {
    float hh[2];
    hh[0] = hp[(size_t)cc * EE];
    hh[1] = hp[(size_t)cc * EE + 16];
    const unsigned short* Bc = Bp + (size_t)cc * 4096;
    bf16x8s bfr[2][4];
#pragma unroll
    for (int s = 0; s < 2; ++s)
#pragma unroll
      for (int nt = 0; nt < 4; ++nt)
        bfr[s][nt] = *(const bf16x8s*)(Bc + (s * 4 + nt) * 512);
    bf16x8s afr[2][2];
#pragma unroll
    for (int mt = 0; mt < 2; ++mt) {
      float hc = hh[mt];
#pragma unroll
      for (int s = 0; s < 2; ++s) {
        BF8 u;
        float4 pa = vs[mt][s][0], pb = vs[mt][s][1];
        u.h[0] = (__bf16)(hc * pa.x); u.h[1] = (__bf16)(hc * pa.y);
        u.h[2] = (__bf16)(hc * pa.z); u.h[3] = (__bf16)(hc * pa.w);
        u.h[4] = (__bf16)(hc * pb.x); u.h[5] = (__bf16)(hc * pb.y);
        u.h[6] = (__bf16)(hc * pb.z); u.h[7] = (__bf16)(hc * pb.w);
        afr[mt][s] = u.v;
      }
    }
#pragma unroll
    for (int s = 0; s < 2; ++s)
#pragma unroll
      for (int mt = 0; mt < 2; ++mt)
#pragma unroll
        for (int nt = 0; nt < 4; ++nt)
          acc[mt][nt] = __builtin_amdgcn_mfma_f32_16x16x32_bf16(
              afr[mt][s], bfr[s][nt], acc[mt][nt], 0, 0, 0);
  }

  if (kchunk == 3) {
    // bias row c = 64 (h == 1)
    const unsigned short* Bc = Bt + (size_t)64 * 4096 + lane * 8;
    bf16x8s bfr[2][4];
#pragma unroll
    for (int s = 0; s < 2; ++s)
#pragma unroll
      for (int nt = 0; nt < 4; ++nt)
        bfr[s][nt] = *(const bf16x8s*)(Bc + (s * 4 + nt) * 512);
    bf16x8s afr[2][2];
#pragma unroll
    for (int mt = 0; mt < 2; ++mt)
#pragma unroll
      for (int s = 0; s < 2; ++s) {
        BF8 u;
        float4 pa = vs[mt][s][0], pb = vs[mt][s][1];
        u.h[0] = (__bf16)pa.x; u.h[1] = (__bf16)pa.y;
        u.h[2] = (__bf16)pa.z; u.h[3] = (__bf16)pa.w;
        u.h[4] = (__bf16)pb.x; u.h[5] = (__bf16)pb.y;
        u.h[6] = (__bf16)pb.z; u.h[7] = (__bf16)pb.w;
        afr[mt][s] = u.v;
      }
#pragma unroll
    for (int s = 0; s < 2; ++s)
#pragma unroll
      for (int mt = 0; mt < 2; ++mt)
#pragma unroll
        for (int nt = 0; nt < 4; ++nt)
          acc[mt][nt] = __builtin_amdgcn_mfma_f32_16x16x32_bf16(
              afr[mt][s], bfr[s][nt], acc[mt][nt], 0, 0, 0);
  }

  // epilogue: C/D row = q*4+r (edge), col = n15; scatter-add by dst
#pragma unroll
  for (int mt = 0; mt < 2; ++mt) {
#pragma unroll
    for (int r = 0; r < 4; ++r) {
      int e = ebase + mt * 16 + q * 4 + r;
      int d = dst[e];
      float* ag = aggr + (size_t)d * HID;
#pragma unroll
      for (int nt = 0; nt < 4; ++nt)
        atomicAdd(ag + nt * 16 + n15, acc[mt][nt][r]);
    }
  }
}

// ------- update(t) [blocks 0..2047] + edge MLP for t+1 [blocks 2048..2111] -------
__global__ __launch_bounds__(256) void k_upd_em(
    float* __restrict__ v, const float* __restrict__ rw, const float* __restrict__ rb,
    float* __restrict__ aggr, const float* __restrict__ degf,
    const float* __restrict__ ear, const float* __restrict__ meanb,
    const float* __restrict__ invstd,
    const float* __restrict__ w1, const float* __restrict__ b1,
    const float* __restrict__ w2, const float* __restrict__ b2,
    float* __restrict__ h2T) {
  int g = threadIdx.x >> 6, lane = threadIdx.x & 63;
  if (blockIdx.x < NN / 4) {
    __shared__ float sh[4][HID];
    int n = blockIdx.x * 4 + g;
    int idx = n * HID + lane;
    sh[g][lane] = v[idx];
    __syncthreads();
    float inv = 1.f / fmaxf(degf[n], 1.f);
    float o = rb[lane] + aggr[idx] * inv;
    aggr[idx] = 0.f;                       // re-zero for next layer
#pragma unroll
    for (int h = 0; h < HID; ++h) o += sh[g][h] * rw[h * HID + lane];
    v[idx] = fmaxf(o, 0.f);
  } else {
    int e = (blockIdx.x - NN / 4) * 256 + threadIdx.x;
    edgemlp_lane(e, ear, meanb, invstd, w1, b1, w2, b2, h2T);
  }
}

// ------- final layer: update(T-1) + proj fused (per-node elementwise) ------------
__global__ __launch_bounds__(256) void k_upd_proj(
    const float* __restrict__ v, const float* __restrict__ rw,
    const float* __restrict__ rb,
    const float* __restrict__ aggr, const float* __restrict__ degf,
    const float* __restrict__ pw1, const float* __restrict__ pb1,
    const float* __restrict__ pw2, const float* __restrict__ pb2,
    float* __restrict__ out) {
  __shared__ float sh[4][HID];
  int g = threadIdx.x >> 6, lane = threadIdx.x & 63;
  int n = blockIdx.x * 4 + g;
  int idx = n * HID + lane;
  sh[g][lane] = v[idx];
  __syncthreads();
  float inv = 1.f / fmaxf(degf[n], 1.f);
  float o = rb[lane] + aggr[idx] * inv;
#pragma unroll
  for (int h = 0; h < HID; ++h) o += sh[g][h] * rw[h * HID + lane];
  float vn = fmaxf(o, 0.f);
  __syncthreads();
  sh[g][lane] = vn;                       // updated v row
  __syncthreads();
  float a = pb1[lane];
#pragma unroll
  for (int h = 0; h < HID; ++h) a += sh[g][h] * pw1[h * HID + lane];
  float h1 = fmaxf(a, 0.f);
  __syncthreads();
  sh[g][lane] = h1;
  __syncthreads();
  if (lane < OUT_DIM) {
    float oo = pb2[lane];
#pragma unroll
    for (int h = 0; h < HID; ++h) oo += sh[g][h] * pw2[h * OUT_DIM + lane];
    out[n * OUT_DIM + lane] = oo;
  }
}

extern "C" void kernel_launch(void* const* d_in, const int* in_sizes, int n_in,
                              void* d_out, int out_size, void* d_ws, size_t ws_size,
                              hipStream_t stream) {
  const float* x        = (const float*)d_in[0];
  const float* ear      = (const float*)d_in[1];
  const float* lift_w1  = (const float*)d_in[2];
  const float* lift_b1  = (const float*)d_in[3];
  const float* lift_w2  = (const float*)d_in[4];
  const float* lift_b2  = (const float*)d_in[5];
  const float* root_w   = (const float*)d_in[6];
  const float* root_b   = (const float*)d_in[7];
  const float* kw1      = (const float*)d_in[8];
  const float* kb1      = (const float*)d_in[9];
  const float* kw2      = (const float*)d_in[10];
  const float* kb2      = (const float*)d_in[11];
  const float* kw3      = (const float*)d_in[12];
  const float* kb3      = (const float*)d_in[13];
  const float* pw1      = (const float*)d_in[14];
  const float* pb1      = (const float*)d_in[15];
  const float* pw2      = (const float*)d_in[16];
  const float* pb2      = (const float*)d_in[17];
  const int* edge_index = (const int*)d_in[18];
  const int* src = edge_index;
  const int* dst = edge_index + EE;
  float* out = (float*)d_out;

  float* ws     = (float*)d_ws;
  float* aggr   = ws;                          // NN*HID
  float* degf   = aggr + NN * HID;             // NN
  float* h2T    = degf + NN;                   // HID*EE (transposed)
  float* vbuf   = h2T + (size_t)HID * EE;      // NN*HID
  float* meanb  = vbuf + NN * HID;             // 72
  float* invstd = meanb + 72;                  // 72
  unsigned short* Bbf = (unsigned short*)(invstd + 72);  // TT*65*4096 bf16

  hipMemsetAsync(degf, 0, NN * sizeof(float), stream);
  const int PRE_BLOCKS = NN / 4 + 1024 + EE / 256 + N_GRAPHS + NN * HID / 1024;
  k_pre<<<PRE_BLOCKS, 256, 0, stream>>>(
      x, lift_w1, lift_b1, lift_w2, lift_b2, vbuf, kw3, kb3, Bbf,
      dst, degf, ear, meanb, invstd, aggr);
  k_em<<<EE / 256, 256, 0, stream>>>(ear, meanb, invstd,
      kw1, kb1, kw2, kb2, h2T);

  for (int t = 0; t < TT; ++t) {
    k_msg<<<512, 256, 0, stream>>>(vbuf, h2T, Bbf + (size_t)t * 65 * 4096,
                                   src, dst, aggr);
    if (t < TT - 1) {
      int tt = t + 1;
      k_upd_em<<<NN / 4 + EE / 256, 256, 0, stream>>>(
          vbuf, root_w + (size_t)t * HID * HID, root_b + (size_t)t * HID,
          aggr, degf, ear, meanb, invstd,
          kw1 + (size_t)tt * EDGE_DIM * HID, kb1 + (size_t)tt * HID,
          kw2 + (size_t)tt * HID * HID, kb2 + (size_t)tt * HID, h2T);
    } else {
      k_upd_proj<<<NN / 4, 256, 0, stream>>>(
          vbuf, root_w + (size_t)t * HID * HID, root_b + (size_t)t * HID,
          aggr, degf, pw1, pb1, pw2, pb2, out);
    }
  }
}

// Round 5
// 416.532 us; speedup vs baseline: 2.2644x; 2.2644x over previous
//
#include <hip/hip_runtime.h>

#define N_GRAPHS    8
#define EDGES_PER_G 2048
#define NN          8192
#define EE          16384
#define IN_DIM      10
#define EDGE_DIM    9
#define HID         64
#define OUT_DIM     3
#define TT          5
#define EPSN        1e-6f

typedef float f32x4 __attribute__((ext_vector_type(4)));
typedef short bf16x8s __attribute__((ext_vector_type(8)));

union BF8 { __bf16 h[8]; bf16x8s v; };

// ------- edge MLP, wave-per-4-edges (lane = channel), transposed h2T output ------
// h2T[c*EE+e] = relu(relu(norm(ear[e]) @ w1 + b1) @ w2 + b2)[c]
// sh/st are [4][HID] LDS staging; no per-thread arrays (avoid scratch spill).
__device__ inline void edgemlp_body_T(int e0, int tid,
    const float* __restrict__ ear, const float* __restrict__ meanb,
    const float* __restrict__ invstd,
    const float* __restrict__ w1, const float* __restrict__ b1,
    const float* __restrict__ w2, const float* __restrict__ b2,
    float (*sh)[HID], float (*st)[HID], float* __restrict__ h2T) {
  int g = tid >> 6, lane = tid & 63;
  int e = e0 + g;
  int gg = e >> 11;                        // 2048 edges per graph
  const float* er = ear + (size_t)e * EDGE_DIM;
  const float* mb = meanb + gg * EDGE_DIM;
  const float* is = invstd + gg * EDGE_DIM;
  float xn[EDGE_DIM];
#pragma unroll
  for (int d = 0; d < EDGE_DIM; ++d) xn[d] = (er[d] - mb[d]) * is[d];
  float a = b1[lane];
#pragma unroll
  for (int d = 0; d < EDGE_DIM; ++d) a += xn[d] * w1[d * HID + lane];
  sh[g][lane] = fmaxf(a, 0.f);
  __syncthreads();
  float o = b2[lane];
#pragma unroll
  for (int h = 0; h < HID; ++h) o += sh[g][h] * w2[h * HID + lane];
  st[g][lane] = fmaxf(o, 0.f);
  __syncthreads();
  // transposed write: thread t -> channel c = t>>2, edge offset eo = t&3
  int c = tid >> 2, eo = tid & 3;
  h2T[(size_t)c * EE + e0 + eo] = st[eo][c];
}

// ---------------- preamble: lift | bprep(permuted) | deg | stats | zero-aggr ------
__global__ __launch_bounds__(256) void k_pre(
    const float* __restrict__ x,
    const float* __restrict__ lw1, const float* __restrict__ lb1,
    const float* __restrict__ lw2, const float* __restrict__ lb2,
    float* __restrict__ v,
    const float* __restrict__ kw3, const float* __restrict__ kb3,
    unsigned short* __restrict__ Bbf,
    const int* __restrict__ dst, float* __restrict__ degf,
    const float* __restrict__ ear, float* __restrict__ meanb,
    float* __restrict__ invstd, float* __restrict__ aggr) {
  __shared__ float sh[4][HID];
  int b = blockIdx.x;
  int g = threadIdx.x >> 6, lane = threadIdx.x & 63;
  if (b < NN / 4) {
    // ---- lift MLP ----
    int n = b * 4 + g;
    const float* xr = x + n * IN_DIM;
    float a = lb1[lane];
#pragma unroll
    for (int d = 0; d < IN_DIM; ++d) a += xr[d] * lw1[d * HID + lane];
    sh[g][lane] = fmaxf(a, 0.f);
    __syncthreads();
    float o = lb2[lane];
#pragma unroll
    for (int h = 0; h < HID; ++h) o += sh[g][h] * lw2[h * HID + lane];
    v[n * HID + lane] = o;
  } else if (b < NN / 4 + 1024) {
    // ---- bprep: kw3 (+kb3 as row 64) -> bf16, FRAGMENT-MAJOR layout:
    //      Bbf[t][c][(s*4+nt)*512 + lane*8 + jj], element = W3[c][nt*16+n15][s*32+q*8+jj]
    const int total = TT * 65 * 4096;
    for (int i = (b - NN / 4) * 256 + (int)threadIdx.x; i < total; i += 1024 * 256) {
      int xx   = i & 4095;
      int call = i >> 12;
      int t = call / 65;
      int c = call - t * 65;
      int sn = xx >> 9;              // s*4+nt
      int s  = sn >> 2, nt = sn & 3;
      int l9 = xx & 511;
      int ln = l9 >> 3, jj = l9 & 7;
      int nn15 = ln & 15, qq = ln >> 4;
      int x_in = (nt * 16 + nn15) * 64 + s * 32 + qq * 8 + jj;
      float val = (c < 64) ? kw3[(size_t)(t * 64 + c) * 4096 + x_in]
                           : kb3[(size_t)t * 4096 + x_in];
      union { __bf16 h; unsigned short s16; } u;
      u.h = (__bf16)val;
      Bbf[i] = u.s16;
    }
  } else if (b < NN / 4 + 1024 + EE / 256) {
    // ---- deg histogram ----
    int e = (b - (NN / 4 + 1024)) * 256 + threadIdx.x;
    atomicAdd(&degf[dst[e]], 1.f);
  } else if (b < NN / 4 + 1024 + EE / 256 + N_GRAPHS) {
    // ---- per-graph edge_attr stats ----
    int gg = b - (NN / 4 + 1024 + EE / 256);
    float* ssum = &sh[0][0];
    float* ssq  = &sh[1][0];
    if (threadIdx.x < EDGE_DIM) { ssum[threadIdx.x] = 0.f; ssq[threadIdx.x] = 0.f; }
    __syncthreads();
    float ls[EDGE_DIM], lq[EDGE_DIM];
#pragma unroll
    for (int d = 0; d < EDGE_DIM; ++d) { ls[d] = 0.f; lq[d] = 0.f; }
    for (int e = threadIdx.x; e < EDGES_PER_G; e += blockDim.x) {
      const float* row = ear + (size_t)(gg * EDGES_PER_G + e) * EDGE_DIM;
#pragma unroll
      for (int d = 0; d < EDGE_DIM; ++d) { float xv = row[d]; ls[d] += xv; lq[d] += xv * xv; }
    }
#pragma unroll
    for (int d = 0; d < EDGE_DIM; ++d) { atomicAdd(&ssum[d], ls[d]); atomicAdd(&ssq[d], lq[d]); }
    __syncthreads();
    if (threadIdx.x < EDGE_DIM) {
      float m  = ssum[threadIdx.x] * (1.0f / EDGES_PER_G);
      float mq = ssq[threadIdx.x] * (1.0f / EDGES_PER_G);
      float var = fmaxf(mq - m * m, 0.f);
      meanb[gg * EDGE_DIM + threadIdx.x]  = m;
      invstd[gg * EDGE_DIM + threadIdx.x] = 1.f / (sqrtf(var) + EPSN);
    }
  } else {
    // ---- zero aggr (float4, 512 blocks) ----
    int idx = (b - (NN / 4 + 1024 + EE / 256 + N_GRAPHS)) * 256 + threadIdx.x;
    ((float4*)aggr)[idx] = make_float4(0.f, 0.f, 0.f, 0.f);
  }
}

// ---------------- standalone edge MLP (layer 0), EE/4 blocks ----------------
__global__ __launch_bounds__(256) void k_em(const float* __restrict__ ear,
    const float* __restrict__ meanb, const float* __restrict__ invstd,
    const float* __restrict__ w1, const float* __restrict__ b1,
    const float* __restrict__ w2, const float* __restrict__ b2,
    float* __restrict__ h2T) {
  __shared__ float sh[4][HID];
  __shared__ float st[4][HID];
  edgemlp_body_T(blockIdx.x * 4, threadIdx.x, ear, meanb, invstd,
                 w1, b1, w2, b2, sh, st, h2T);
}

// ---------------- msg GEMM: Msg[E,64] = A[E,4160] @ B[4160,64], scatter by dst ----
// A[e, c*64+j] = h2[e,c] * v[src[e], j]  (row c==64: h2==1 -> bias b3)
// B in fragment-major layout: every fragment load is base + lane*16 (coalesced).
// h2 in transposed layout h2T[c][e]: per-iter load = 16 consecutive floats.
__global__ __launch_bounds__(256) void k_msg(const float* __restrict__ v,
    const float* __restrict__ h2T, const unsigned short* __restrict__ Bt,
    const int* __restrict__ src, const int* __restrict__ dst,
    float* __restrict__ aggr) {
  int kchunk = blockIdx.x & 3;
  int ebb    = (blockIdx.x >> 2) * 128;
  int w    = threadIdx.x >> 6;
  int lane = threadIdx.x & 63;
  int n15  = lane & 15;
  int q    = lane >> 4;
  int ebase = ebb + w * 32;

  float4 vs[2][2][2];   // [m-tile][k-step s][half]: v[src[e]][s*32 + q*8 .. +8]
#pragma unroll
  for (int mt = 0; mt < 2; ++mt) {
    int e = ebase + mt * 16 + n15;
    const float4* vr = (const float4*)(v + (size_t)src[e] * HID);
    int f0 = q * 2;
    vs[mt][0][0] = vr[f0];     vs[mt][0][1] = vr[f0 + 1];
    vs[mt][1][0] = vr[8 + f0]; vs[mt][1][1] = vr[8 + f0 + 1];
  }

  f32x4 acc[2][4];
#pragma unroll
  for (int mt = 0; mt < 2; ++mt)
#pragma unroll
    for (int nt = 0; nt < 4; ++nt) acc[mt][nt] = (f32x4)0.0f;

  int c0 = kchunk * 16;
  const unsigned short* Bp = Bt + (size_t)c0 * 4096 + lane * 8;
  const float* hp = h2T + (size_t)c0 * EE + ebase + n15;

#pragma unroll 4
  for (int cc = 0; cc < 16; ++cc) {
    float hh[2];
    hh[0] = hp[(size_t)cc * EE];
    hh[1] = hp[(size_t)cc * EE + 16];
    const unsigned short* Bc = Bp + (size_t)cc * 4096;
    bf16x8s bfr[2][4];
#pragma unroll
    for (int s = 0; s < 2; ++s)
#pragma unroll
      for (int nt = 0; nt < 4; ++nt)
        bfr[s][nt] = *(const bf16x8s*)(Bc + (s * 4 + nt) * 512);
    bf16x8s afr[2][2];
#pragma unroll
    for (int mt = 0; mt < 2; ++mt) {
      float hc = hh[mt];
#pragma unroll
      for (int s = 0; s < 2; ++s) {
        BF8 u;
        float4 pa = vs[mt][s][0], pb = vs[mt][s][1];
        u.h[0] = (__bf16)(hc * pa.x); u.h[1] = (__bf16)(hc * pa.y);
        u.h[2] = (__bf16)(hc * pa.z); u.h[3] = (__bf16)(hc * pa.w);
        u.h[4] = (__bf16)(hc * pb.x); u.h[5] = (__bf16)(hc * pb.y);
        u.h[6] = (__bf16)(hc * pb.z); u.h[7] = (__bf16)(hc * pb.w);
        afr[mt][s] = u.v;
      }
    }
#pragma unroll
    for (int s = 0; s < 2; ++s)
#pragma unroll
      for (int mt = 0; mt < 2; ++mt)
#pragma unroll
        for (int nt = 0; nt < 4; ++nt)
          acc[mt][nt] = __builtin_amdgcn_mfma_f32_16x16x32_bf16(
              afr[mt][s], bfr[s][nt], acc[mt][nt], 0, 0, 0);
  }

  if (kchunk == 3) {
    // bias row c = 64 (h == 1)
    const unsigned short* Bc = Bt + (size_t)64 * 4096 + lane * 8;
    bf16x8s bfr[2][4];
#pragma unroll
    for (int s = 0; s < 2; ++s)
#pragma unroll
      for (int nt = 0; nt < 4; ++nt)
        bfr[s][nt] = *(const bf16x8s*)(Bc + (s * 4 + nt) * 512);
    bf16x8s afr[2][2];
#pragma unroll
    for (int mt = 0; mt < 2; ++mt)
#pragma unroll
      for (int s = 0; s < 2; ++s) {
        BF8 u;
        float4 pa = vs[mt][s][0], pb = vs[mt][s][1];
        u.h[0] = (__bf16)pa.x; u.h[1] = (__bf16)pa.y;
        u.h[2] = (__bf16)pa.z; u.h[3] = (__bf16)pa.w;
        u.h[4] = (__bf16)pb.x; u.h[5] = (__bf16)pb.y;
        u.h[6] = (__bf16)pb.z; u.h[7] = (__bf16)pb.w;
        afr[mt][s] = u.v;
      }
#pragma unroll
    for (int s = 0; s < 2; ++s)
#pragma unroll
      for (int mt = 0; mt < 2; ++mt)
#pragma unroll
        for (int nt = 0; nt < 4; ++nt)
          acc[mt][nt] = __builtin_amdgcn_mfma_f32_16x16x32_bf16(
              afr[mt][s], bfr[s][nt], acc[mt][nt], 0, 0, 0);
  }

  // epilogue: C/D row = q*4+r (edge), col = n15; scatter-add by dst
#pragma unroll
  for (int mt = 0; mt < 2; ++mt) {
#pragma unroll
    for (int r = 0; r < 4; ++r) {
      int e = ebase + mt * 16 + q * 4 + r;
      int d = dst[e];
      float* ag = aggr + (size_t)d * HID;
#pragma unroll
      for (int nt = 0; nt < 4; ++nt)
        atomicAdd(ag + nt * 16 + n15, acc[mt][nt][r]);
    }
  }
}

// ------- update(t) [blocks 0..2047] + edge MLP for t+1 [blocks 2048..6143] -------
__global__ __launch_bounds__(256) void k_upd_em(
    float* __restrict__ v, const float* __restrict__ rw, const float* __restrict__ rb,
    float* __restrict__ aggr, const float* __restrict__ degf,
    const float* __restrict__ ear, const float* __restrict__ meanb,
    const float* __restrict__ invstd,
    const float* __restrict__ w1, const float* __restrict__ b1,
    const float* __restrict__ w2, const float* __restrict__ b2,
    float* __restrict__ h2T) {
  __shared__ float sh[4][HID];
  __shared__ float st[4][HID];
  int g = threadIdx.x >> 6, lane = threadIdx.x & 63;
  if (blockIdx.x < NN / 4) {
    int n = blockIdx.x * 4 + g;
    int idx = n * HID + lane;
    sh[g][lane] = v[idx];
    __syncthreads();
    float inv = 1.f / fmaxf(degf[n], 1.f);
    float o = rb[lane] + aggr[idx] * inv;
    aggr[idx] = 0.f;                       // re-zero for next layer
#pragma unroll
    for (int h = 0; h < HID; ++h) o += sh[g][h] * rw[h * HID + lane];
    v[idx] = fmaxf(o, 0.f);
  } else {
    int e0 = (blockIdx.x - NN / 4) * 4;
    edgemlp_body_T(e0, threadIdx.x, ear, meanb, invstd,
                   w1, b1, w2, b2, sh, st, h2T);
  }
}

// ------- final layer: update(T-1) + proj fused (per-node elementwise) ------------
__global__ __launch_bounds__(256) void k_upd_proj(
    const float* __restrict__ v, const float* __restrict__ rw,
    const float* __restrict__ rb,
    const float* __restrict__ aggr, const float* __restrict__ degf,
    const float* __restrict__ pw1, const float* __restrict__ pb1,
    const float* __restrict__ pw2, const float* __restrict__ pb2,
    float* __restrict__ out) {
  __shared__ float sh[4][HID];
  int g = threadIdx.x >> 6, lane = threadIdx.x & 63;
  int n = blockIdx.x * 4 + g;
  int idx = n * HID + lane;
  sh[g][lane] = v[idx];
  __syncthreads();
  float inv = 1.f / fmaxf(degf[n], 1.f);
  float o = rb[lane] + aggr[idx] * inv;
#pragma unroll
  for (int h = 0; h < HID; ++h) o += sh[g][h] * rw[h * HID + lane];
  float vn = fmaxf(o, 0.f);
  __syncthreads();
  sh[g][lane] = vn;                       // updated v row
  __syncthreads();
  float a = pb1[lane];
#pragma unroll
  for (int h = 0; h < HID; ++h) a += sh[g][h] * pw1[h * HID + lane];
  float h1 = fmaxf(a, 0.f);
  __syncthreads();
  sh[g][lane] = h1;
  __syncthreads();
  if (lane < OUT_DIM) {
    float oo = pb2[lane];
#pragma unroll
    for (int h = 0; h < HID; ++h) oo += sh[g][h] * pw2[h * OUT_DIM + lane];
    out[n * OUT_DIM + lane] = oo;
  }
}

extern "C" void kernel_launch(void* const* d_in, const int* in_sizes, int n_in,
                              void* d_out, int out_size, void* d_ws, size_t ws_size,
                              hipStream_t stream) {
  const float* x        = (const float*)d_in[0];
  const float* ear      = (const float*)d_in[1];
  const float* lift_w1  = (const float*)d_in[2];
  const float* lift_b1  = (const float*)d_in[3];
  const float* lift_w2  = (const float*)d_in[4];
  const float* lift_b2  = (const float*)d_in[5];
  const float* root_w   = (const float*)d_in[6];
  const float* root_b   = (const float*)d_in[7];
  const float* kw1      = (const float*)d_in[8];
  const float* kb1      = (const float*)d_in[9];
  const float* kw2      = (const float*)d_in[10];
  const float* kb2      = (const float*)d_in[11];
  const float* kw3      = (const float*)d_in[12];
  const float* kb3      = (const float*)d_in[13];
  const float* pw1      = (const float*)d_in[14];
  const float* pb1      = (const float*)d_in[15];
  const float* pw2      = (const float*)d_in[16];
  const float* pb2      = (const float*)d_in[17];
  const int* edge_index = (const int*)d_in[18];
  const int* src = edge_index;
  const int* dst = edge_index + EE;
  float* out = (float*)d_out;

  float* ws     = (float*)d_ws;
  float* aggr   = ws;                          // NN*HID
  float* degf   = aggr + NN * HID;             // NN
  float* h2T    = degf + NN;                   // HID*EE (transposed)
  float* vbuf   = h2T + (size_t)HID * EE;      // NN*HID
  float* meanb  = vbuf + NN * HID;             // 72
  float* invstd = meanb + 72;                  // 72
  unsigned short* Bbf = (unsigned short*)(invstd + 72);  // TT*65*4096 bf16

  hipMemsetAsync(degf, 0, NN * sizeof(float), stream);
  const int PRE_BLOCKS = NN / 4 + 1024 + EE / 256 + N_GRAPHS + NN * HID / 1024;
  k_pre<<<PRE_BLOCKS, 256, 0, stream>>>(
      x, lift_w1, lift_b1, lift_w2, lift_b2, vbuf, kw3, kb3, Bbf,
      dst, degf, ear, meanb, invstd, aggr);
  k_em<<<EE / 4, 256, 0, stream>>>(ear, meanb, invstd,
      kw1, kb1, kw2, kb2, h2T);

  for (int t = 0; t < TT; ++t) {
    k_msg<<<512, 256, 0, stream>>>(vbuf, h2T, Bbf + (size_t)t * 65 * 4096,
                                   src, dst, aggr);
    if (t < TT - 1) {
      int tt = t + 1;
      k_upd_em<<<NN / 4 + EE / 4, 256, 0, stream>>>(
          vbuf, root_w + (size_t)t * HID * HID, root_b + (size_t)t * HID,
          aggr, degf, ear, meanb, invstd,
          kw1 + (size_t)tt * EDGE_DIM * HID, kb1 + (size_t)tt * HID,
          kw2 + (size_t)tt * HID * HID, kb2 + (size_t)tt * HID, h2T);
    } else {
      k_upd_proj<<<NN / 4, 256, 0, stream>>>(
          vbuf, root_w + (size_t)t * HID * HID, root_b + (size_t)t * HID,
          aggr, degf, pw1, pb1, pw2, pb2, out);
    }
  }
}